// Round 3
// baseline (409.967 us; speedup 1.0000x reference)
//
#include <hip/hip_runtime.h>
#include <stdint.h>

typedef unsigned long long u64;
typedef unsigned int u32;

#define NB 32     // batches
#define NP 8192   // points per batch
#define NG 256    // FPS centers
#define NK 32     // neighbors per center

// Exact IEEE ops (block FMA contraction so we bit-match the numpy reference):
// d = ((dx*dx) + (dy*dy)) + (dz*dz)
__device__ __forceinline__ float dist3(float dx, float dy, float dz) {
    return __fadd_rn(__fadd_rn(__fmul_rn(dx, dx), __fmul_rn(dy, dy)), __fmul_rn(dz, dz));
}

// ---- DPP wave reductions (VALU-only, no LDS pipe) ----------------------------
#define DPP_STEP(v, ctrl, rmask) __builtin_amdgcn_update_dpp((int)(v), (int)(v), (ctrl), (rmask), 0xf, false)

__device__ __forceinline__ u32 wave_max_u32(u32 v) {
    u32 o;
    o = (u32)DPP_STEP(v, 0x111, 0xf); v = (o > v) ? o : v;  // row_shr:1
    o = (u32)DPP_STEP(v, 0x112, 0xf); v = (o > v) ? o : v;  // row_shr:2
    o = (u32)DPP_STEP(v, 0x114, 0xf); v = (o > v) ? o : v;  // row_shr:4
    o = (u32)DPP_STEP(v, 0x118, 0xf); v = (o > v) ? o : v;  // row_shr:8
    o = (u32)DPP_STEP(v, 0x142, 0xa); v = (o > v) ? o : v;  // row_bcast:15
    o = (u32)DPP_STEP(v, 0x143, 0xc); v = (o > v) ? o : v;  // row_bcast:31
    return (u32)__builtin_amdgcn_readlane((int)v, 63);
}

__device__ __forceinline__ u32 wave_min_u32(u32 v) {
    u32 o;
    o = (u32)DPP_STEP(v, 0x111, 0xf); v = (o < v) ? o : v;
    o = (u32)DPP_STEP(v, 0x112, 0xf); v = (o < v) ? o : v;
    o = (u32)DPP_STEP(v, 0x114, 0xf); v = (o < v) ? o : v;
    o = (u32)DPP_STEP(v, 0x118, 0xf); v = (o < v) ? o : v;
    o = (u32)DPP_STEP(v, 0x142, 0xa); v = (o < v) ? o : v;
    o = (u32)DPP_STEP(v, 0x143, 0xc); v = (o < v) ? o : v;
    return (u32)__builtin_amdgcn_readlane((int)v, 63);
}

// ---------------------------------------------------------------------------
// Kernel 1: farthest point sampling. One block (512 threads, 8 waves) per
// batch; 16 register-resident points per thread (launch_bounds(512,2) gives a
// 256-VGPR budget so nothing spills — at default bounds the compiler chose 44
// VGPRs and spilled the point arrays to scratch, ~2x the whole kernel cost).
// One barrier per iteration (parity-double-buffered wavekey); next centroid
// re-fetched by all lanes via a scalar (readfirstlane) load.
// Bit-exact vs reference: dist = min(dist, ((dx*dx)+(dy*dy))+(dz*dz));
// argmax = first index of max.
// ---------------------------------------------------------------------------
__global__ __launch_bounds__(512, 2) void fps_kernel(const float* __restrict__ xyz,
                                                     float* __restrict__ out)
{
    const int b = blockIdx.x;
    const int t = threadIdx.x;
    const int wid = t >> 6, lane = t & 63;

    __shared__ u64 wavekey[2][8];

    const float* base = xyz + (size_t)b * NP * 3;

    float px[16], py[16], pz[16], dist[16];
    {
        const float4* src = reinterpret_cast<const float4*>(base) + t * 12;
        float4 f[12];
        #pragma unroll
        for (int i = 0; i < 12; ++i) f[i] = src[i];
        float fl[48];
        #pragma unroll
        for (int i = 0; i < 12; ++i) {
            fl[4*i] = f[i].x; fl[4*i+1] = f[i].y; fl[4*i+2] = f[i].z; fl[4*i+3] = f[i].w;
        }
        #pragma unroll
        for (int j = 0; j < 16; ++j) {
            px[j] = fl[3*j]; py[j] = fl[3*j+1]; pz[j] = fl[3*j+2];
            dist[j] = 1e10f;
        }
    }

    // first centroid = point 0
    float cx, cy, cz;
    {
        float4 f0 = *reinterpret_cast<const float4*>(base);
        cx = f0.x; cy = f0.y; cz = f0.z;
        if (t == 0) {
            float* o = out + (size_t)b * NG * 3;
            o[0] = cx; o[1] = cy; o[2] = cz;
        }
    }

    for (int g = 0; g < NG - 1; ++g) {
        #pragma unroll
        for (int j = 0; j < 16; ++j) {
            float dx = __fsub_rn(px[j], cx);
            float dy = __fsub_rn(py[j], cy);
            float dz = __fsub_rn(pz[j], cz);
            float d  = dist3(dx, dy, dz);
            dist[j] = fminf(dist[j], d);
        }
        // max3-friendly tree max over the 16 updated dists
        float m0 = fmaxf(fmaxf(dist[0],  dist[1]),  dist[2]);
        float m1 = fmaxf(fmaxf(dist[3],  dist[4]),  dist[5]);
        float m2 = fmaxf(fmaxf(dist[6],  dist[7]),  dist[8]);
        float m3 = fmaxf(fmaxf(dist[9],  dist[10]), dist[11]);
        float m4 = fmaxf(fmaxf(dist[12], dist[13]), dist[14]);
        float m5 = fmaxf(fmaxf(m0, m1), m2);
        float m6 = fmaxf(fmaxf(m3, m4), dist[15]);
        float bestd = fmaxf(m5, m6);

        u32 hi = __float_as_uint(bestd);      // dist >= 0 -> bits order-monotone
        u32 mh = wave_max_u32(hi);
        u32 cl = 0;
        if (hi == mh) {
            // rare path (~1 thread/block): recover FIRST local index of the max
            u32 bestj = 0;
            #pragma unroll
            for (int j = 15; j >= 0; --j)
                if (dist[j] == bestd) bestj = (u32)j;
            cl = (u32)(NP - 1 - (t * 16 + (int)bestj));   // larger = smaller idx
        }
        u32 ml = wave_max_u32(cl);
        if (lane == 0) wavekey[g & 1][wid] = ((u64)mh << 32) | (u64)ml;
        __syncthreads();

        u64 wk = wavekey[g & 1][0];
        #pragma unroll
        for (int w = 1; w < 8; ++w) {
            u64 o = wavekey[g & 1][w];
            wk = (o > wk) ? o : wk;
        }
        const int widx = NP - 1 - (int)(u32)(wk & 0xFFFFFFFFull);
        const int uw   = __builtin_amdgcn_readfirstlane(widx);   // scalar load path
        const float* cp = base + (size_t)uw * 3;
        cx = cp[0]; cy = cp[1]; cz = cp[2];
        if (t == 0) {
            float* o = out + ((size_t)b * NG + g + 1) * 3;
            o[0] = cx; o[1] = cy; o[2] = cz;
        }
    }
}

// ---------------------------------------------------------------------------
// Kernel 2: 32-NN mean per (batch, center). One WAVE per task. Each lane
// streams 128 points keeping its 4 smallest packed keys. 32 extraction
// rounds: DPP u32-min on dist bits; tie-break to smallest index is FREE —
// lane l owns indices [l*128, l*128+128) (disjoint, ascending in l), and its
// sorted t0 carries its smallest tied idx, so the winner is the LOWEST lane
// matching the min (ballot + ffs + readlane). Exact lazy rescan (filter
// key > lane's last extracted) if a lane's 4-entry list empties (~1%/task).
// ---------------------------------------------------------------------------
__device__ __forceinline__ void build_top4(const float4* __restrict__ src,
                                           float cx, float cy, float cz, float s2,
                                           u64 L, bool useL, int lane,
                                           u64& t0, u64& t1, u64& t2, u64& t3)
{
    t0 = t1 = t2 = t3 = ~0ull;
    #pragma unroll 4
    for (int q = 0; q < 32; ++q) {
        float4 f0 = src[q*3+0];
        float4 f1 = src[q*3+1];
        float4 f2 = src[q*3+2];
        float a[12] = {f0.x,f0.y,f0.z,f0.w, f1.x,f1.y,f1.z,f1.w, f2.x,f2.y,f2.z,f2.w};
        #pragma unroll
        for (int rr = 0; rr < 4; ++rr) {
            float nx = a[rr*3+0], ny = a[rr*3+1], nz = a[rr*3+2];
            // reference: (||s||^2 - 2*(s.n)) + ||n||^2, left-to-right, no FMA
            float dotv = __fadd_rn(__fadd_rn(__fmul_rn(cx,nx), __fmul_rn(cy,ny)), __fmul_rn(cz,nz));
            float n2   = dist3(nx, ny, nz);
            float d    = __fadd_rn(__fsub_rn(s2, __fmul_rn(2.0f, dotv)), n2);
            // monotone map f32 -> u32 (handles the tiny-negative self-distance)
            u32 u  = __float_as_uint(d);
            u32 kk = u ^ (u32)(((int)u >> 31) | 0x80000000);
            int idx = lane * 128 + q * 4 + rr;
            u64 pk = ((u64)kk << 32) | (u64)(u32)idx;
            if (!useL || pk > L) {
                if (pk < t3) {
                    t3 = pk;
                    if (t3 < t2) { u64 tmp = t2; t2 = t3; t3 = tmp; }
                    if (t2 < t1) { u64 tmp = t1; t1 = t2; t2 = tmp; }
                    if (t1 < t0) { u64 tmp = t0; t0 = t1; t1 = tmp; }
                }
            }
        }
    }
}

__global__ __launch_bounds__(256) void knn_kernel(const float* __restrict__ xyz,
                                                  float* __restrict__ out)
{
    const int t    = threadIdx.x;
    const int lane = t & 63;
    const int wid  = t >> 6;
    const int task = blockIdx.x * 4 + wid;   // 0..8191
    const int b    = task >> 8;
    const int g    = task & 255;

    const float* cptr = out + ((size_t)b * NG + g) * 3;   // centers from fps_kernel
    const float cx = cptr[0], cy = cptr[1], cz = cptr[2];
    const float s2 = dist3(cx, cy, cz);

    const float4* src = reinterpret_cast<const float4*>(xyz + (size_t)b * NP * 3) + (size_t)lane * 96;

    u64 t0, t1, t2, t3;
    build_top4(src, cx, cy, cz, s2, 0ull, false, lane, t0, t1, t2, t3);
    int cnt = 4;
    u64 L = 0;
    u32 myWin = 0;

    for (int round = 0; round < NK; ++round) {
        if (cnt == 0) {
            build_top4(src, cx, cy, cz, s2, L, true, lane, t0, t1, t2, t3);
            cnt = 4;
        }
        u32 hi0 = (u32)(t0 >> 32);
        u32 lo0 = (u32)(t0 & 0xFFFFFFFFull);
        u32 mh = wave_min_u32(hi0);
        u64 bmask = __ballot(hi0 == mh);
        int owner = __ffsll((unsigned long long)bmask) - 1;  // lowest lane = smallest idx
        u32 widx = (u32)__builtin_amdgcn_readlane((int)lo0, owner);
        if (lane == owner) {
            L = t0;
            t0 = t1; t1 = t2; t2 = t3; t3 = ~0ull;
            --cnt;
        }
        if (lane == round) myWin = widx;
    }

    float sx = 0.f, sy = 0.f, sz = 0.f;
    if (lane < NK) {
        const float* p = xyz + ((size_t)b * NP + myWin) * 3;
        sx = p[0]; sy = p[1]; sz = p[2];
    }
    #pragma unroll
    for (int m = 32; m >= 1; m >>= 1) {
        sx += __shfl_xor(sx, m, 64);
        sy += __shfl_xor(sy, m, 64);
        sz += __shfl_xor(sz, m, 64);
    }
    if (lane == 0) {
        float* o = out + (size_t)NB * NG * 3 + ((size_t)b * NG + g) * 3;
        const float inv = 1.0f / 32.0f;   // /32 exact (power of 2)
        o[0] = sx * inv; o[1] = sy * inv; o[2] = sz * inv;
    }
}

extern "C" void kernel_launch(void* const* d_in, const int* in_sizes, int n_in,
                              void* d_out, int out_size, void* d_ws, size_t ws_size,
                              hipStream_t stream)
{
    const float* xyz = (const float*)d_in[0];
    float* out = (float*)d_out;

    hipLaunchKernelGGL(fps_kernel, dim3(NB), dim3(512), 0, stream, xyz, out);

    const int tasks  = NB * NG;            // 8192
    const int blocks = tasks / 4;          // 4 waves (tasks) per 256-thread block
    hipLaunchKernelGGL(knn_kernel, dim3(blocks), dim3(256), 0, stream, xyz, out);
}

// Round 4
// 396.571 us; speedup vs baseline: 1.0338x; 1.0338x over previous
//
#include <hip/hip_runtime.h>
#include <stdint.h>

typedef unsigned long long u64;
typedef unsigned int u32;

#define NB 32     // batches
#define NP 8192   // points per batch
#define NG 256    // FPS centers
#define NK 32     // neighbors per center

// Exact IEEE ops (block FMA contraction so we bit-match the numpy reference):
// d = ((dx*dx) + (dy*dy)) + (dz*dz)
__device__ __forceinline__ float dist3(float dx, float dy, float dz) {
    return __fadd_rn(__fadd_rn(__fmul_rn(dx, dx), __fmul_rn(dy, dy)), __fmul_rn(dz, dz));
}

// ---- DPP wave reductions (VALU-only, no LDS pipe) ----------------------------
#define DPP_STEP(v, ctrl, rmask) __builtin_amdgcn_update_dpp((int)(v), (int)(v), (ctrl), (rmask), 0xf, false)

__device__ __forceinline__ u32 wave_max_u32(u32 v) {
    u32 o;
    o = (u32)DPP_STEP(v, 0x111, 0xf); v = (o > v) ? o : v;  // row_shr:1
    o = (u32)DPP_STEP(v, 0x112, 0xf); v = (o > v) ? o : v;  // row_shr:2
    o = (u32)DPP_STEP(v, 0x114, 0xf); v = (o > v) ? o : v;  // row_shr:4
    o = (u32)DPP_STEP(v, 0x118, 0xf); v = (o > v) ? o : v;  // row_shr:8
    o = (u32)DPP_STEP(v, 0x142, 0xa); v = (o > v) ? o : v;  // row_bcast:15
    o = (u32)DPP_STEP(v, 0x143, 0xc); v = (o > v) ? o : v;  // row_bcast:31
    return (u32)__builtin_amdgcn_readlane((int)v, 63);
}

__device__ __forceinline__ u32 wave_min_u32(u32 v) {
    u32 o;
    o = (u32)DPP_STEP(v, 0x111, 0xf); v = (o < v) ? o : v;
    o = (u32)DPP_STEP(v, 0x112, 0xf); v = (o < v) ? o : v;
    o = (u32)DPP_STEP(v, 0x114, 0xf); v = (o < v) ? o : v;
    o = (u32)DPP_STEP(v, 0x118, 0xf); v = (o < v) ? o : v;
    o = (u32)DPP_STEP(v, 0x142, 0xa); v = (o < v) ? o : v;
    o = (u32)DPP_STEP(v, 0x143, 0xc); v = (o < v) ? o : v;
    return (u32)__builtin_amdgcn_readlane((int)v, 63);
}

// ---------------------------------------------------------------------------
// Kernel 1: farthest point sampling. One block (512 threads, 8 waves) per
// batch; 16 points per thread. The asm pins below force the loaded point
// coords to STAY in VGPRs: without them the allocator rematerializes the
// global loads inside the loop (VGPR_Count=44 with no scratch stores — the
// round-3 counters' signature), re-streaming 96KB/block every iteration.
// One barrier per iteration (parity-double-buffered wavekey); next centroid
// re-fetched by all lanes via a same-address (broadcast) vector load.
// Bit-exact vs reference: dist = min(dist, ((dx*dx)+(dy*dy))+(dz*dz));
// argmax = first index of max (ties -> larger NP-1-idx = smaller idx).
// ---------------------------------------------------------------------------
__global__ __launch_bounds__(512, 2) void fps_kernel(const float* __restrict__ xyz,
                                                     float* __restrict__ out)
{
    const int b = blockIdx.x;
    const int t = threadIdx.x;
    const int wid = t >> 6, lane = t & 63;

    __shared__ u64 wavekey[2][8];

    const float* base = xyz + (size_t)b * NP * 3;

    float px[16], py[16], pz[16], dist[16];
    {
        const float4* src = reinterpret_cast<const float4*>(base) + t * 12;
        float4 f[12];
        #pragma unroll
        for (int i = 0; i < 12; ++i) f[i] = src[i];
        float fl[48];
        #pragma unroll
        for (int i = 0; i < 12; ++i) {
            fl[4*i] = f[i].x; fl[4*i+1] = f[i].y; fl[4*i+2] = f[i].z; fl[4*i+3] = f[i].w;
        }
        #pragma unroll
        for (int j = 0; j < 16; ++j) {
            px[j] = fl[3*j]; py[j] = fl[3*j+1]; pz[j] = fl[3*j+2];
            dist[j] = 1e10f;
        }
    }
    // Liveness pin: block rematerialization of the loads (see header comment).
    #pragma unroll
    for (int j = 0; j < 16; ++j) {
        asm volatile("" : "+v"(px[j]), "+v"(py[j]), "+v"(pz[j]));
    }

    // first centroid = point 0
    float cx, cy, cz;
    {
        float4 f0 = *reinterpret_cast<const float4*>(base);
        cx = f0.x; cy = f0.y; cz = f0.z;
        if (t == 0) {
            float* o = out + (size_t)b * NG * 3;
            o[0] = cx; o[1] = cy; o[2] = cz;
        }
    }

    for (int g = 0; g < NG - 1; ++g) {
        #pragma unroll
        for (int j = 0; j < 16; ++j) {
            float dx = __fsub_rn(px[j], cx);
            float dy = __fsub_rn(py[j], cy);
            float dz = __fsub_rn(pz[j], cz);
            float d  = dist3(dx, dy, dz);
            dist[j] = fminf(dist[j], d);
        }
        // tree max over the 16 updated dists (max3-friendly)
        float m0 = fmaxf(fmaxf(dist[0],  dist[1]),  dist[2]);
        float m1 = fmaxf(fmaxf(dist[3],  dist[4]),  dist[5]);
        float m2 = fmaxf(fmaxf(dist[6],  dist[7]),  dist[8]);
        float m3 = fmaxf(fmaxf(dist[9],  dist[10]), dist[11]);
        float m4 = fmaxf(fmaxf(dist[12], dist[13]), dist[14]);
        float m5 = fmaxf(fmaxf(m0, m1), m2);
        float m6 = fmaxf(fmaxf(m3, m4), dist[15]);
        float bestd = fmaxf(m5, m6);

        u32 hi = __float_as_uint(bestd);      // dist >= 0 -> bits order-monotone
        u32 mh = wave_max_u32(hi);
        u32 cl = 0;
        if (hi == mh) {
            // recover FIRST local index of the max (>=1 lane per wave runs this)
            u32 bestj = 0;
            #pragma unroll
            for (int j = 15; j >= 0; --j)
                if (dist[j] == bestd) bestj = (u32)j;
            cl = (u32)(NP - 1 - (t * 16 + (int)bestj));   // larger = smaller idx
        }
        u32 ml = wave_max_u32(cl);
        if (lane == 0) wavekey[g & 1][wid] = ((u64)mh << 32) | (u64)ml;
        __syncthreads();

        u64 wk = wavekey[g & 1][0];
        #pragma unroll
        for (int w = 1; w < 8; ++w) {
            u64 o = wavekey[g & 1][w];
            wk = (o > wk) ? o : wk;
        }
        const int widx = NP - 1 - (int)(u32)(wk & 0xFFFFFFFFull);
        // broadcast fetch of the new centroid (same address in all lanes; L2-hot)
        const float* cp = base + (size_t)widx * 3;
        cx = cp[0]; cy = cp[1]; cz = cp[2];
        if (t == 0) {
            float* o = out + ((size_t)b * NG + g + 1) * 3;
            o[0] = cx; o[1] = cy; o[2] = cz;
        }
    }
}

// ---------------------------------------------------------------------------
// Kernel 2: 32-NN mean per (batch, center). One WAVE per task. Each lane
// streams 128 points keeping its 4 smallest packed keys. 32 extraction
// rounds: DPP u32-min on dist bits; tie-break to smallest index is free —
// lane l owns a disjoint ascending index range and its sorted t0 carries its
// smallest tied idx, so the winner is the LOWEST lane matching the min
// (ballot + ffs + readlane). Exact lazy rescan (filter key > lane's last
// extracted) if a lane's 4-entry list empties (~1%/task).
// ---------------------------------------------------------------------------
__device__ __forceinline__ void build_top4(const float4* __restrict__ src,
                                           float cx, float cy, float cz, float s2,
                                           u64 L, bool useL, int lane,
                                           u64& t0, u64& t1, u64& t2, u64& t3)
{
    t0 = t1 = t2 = t3 = ~0ull;
    #pragma unroll 4
    for (int q = 0; q < 32; ++q) {
        float4 f0 = src[q*3+0];
        float4 f1 = src[q*3+1];
        float4 f2 = src[q*3+2];
        float a[12] = {f0.x,f0.y,f0.z,f0.w, f1.x,f1.y,f1.z,f1.w, f2.x,f2.y,f2.z,f2.w};
        #pragma unroll
        for (int rr = 0; rr < 4; ++rr) {
            float nx = a[rr*3+0], ny = a[rr*3+1], nz = a[rr*3+2];
            // reference: (||s||^2 - 2*(s.n)) + ||n||^2, left-to-right, no FMA
            float dotv = __fadd_rn(__fadd_rn(__fmul_rn(cx,nx), __fmul_rn(cy,ny)), __fmul_rn(cz,nz));
            float n2   = dist3(nx, ny, nz);
            float d    = __fadd_rn(__fsub_rn(s2, __fmul_rn(2.0f, dotv)), n2);
            // monotone map f32 -> u32 (handles the tiny-negative self-distance)
            u32 u  = __float_as_uint(d);
            u32 kk = u ^ (u32)(((int)u >> 31) | 0x80000000);
            int idx = lane * 128 + q * 4 + rr;
            u64 pk = ((u64)kk << 32) | (u64)(u32)idx;
            if (!useL || pk > L) {
                if (pk < t3) {
                    t3 = pk;
                    if (t3 < t2) { u64 tmp = t2; t2 = t3; t3 = tmp; }
                    if (t2 < t1) { u64 tmp = t1; t1 = t2; t2 = tmp; }
                    if (t1 < t0) { u64 tmp = t0; t0 = t1; t1 = tmp; }
                }
            }
        }
    }
}

__global__ __launch_bounds__(256) void knn_kernel(const float* __restrict__ xyz,
                                                  float* __restrict__ out)
{
    const int t    = threadIdx.x;
    const int lane = t & 63;
    const int wid  = t >> 6;
    const int task = blockIdx.x * 4 + wid;   // 0..8191
    const int b    = task >> 8;
    const int g    = task & 255;

    const float* cptr = out + ((size_t)b * NG + g) * 3;   // centers from fps_kernel
    const float cx = cptr[0], cy = cptr[1], cz = cptr[2];
    const float s2 = dist3(cx, cy, cz);

    const float4* src = reinterpret_cast<const float4*>(xyz + (size_t)b * NP * 3) + (size_t)lane * 96;

    u64 t0, t1, t2, t3;
    build_top4(src, cx, cy, cz, s2, 0ull, false, lane, t0, t1, t2, t3);
    int cnt = 4;
    u64 L = 0;
    u32 myWin = 0;

    for (int round = 0; round < NK; ++round) {
        if (cnt == 0) {
            build_top4(src, cx, cy, cz, s2, L, true, lane, t0, t1, t2, t3);
            cnt = 4;
        }
        u32 hi0 = (u32)(t0 >> 32);
        u32 lo0 = (u32)(t0 & 0xFFFFFFFFull);
        u32 mh = wave_min_u32(hi0);
        u64 bmask = __ballot(hi0 == mh);
        int owner = __ffsll((unsigned long long)bmask) - 1;  // lowest lane = smallest idx
        u32 widx = (u32)__builtin_amdgcn_readlane((int)lo0, owner);
        if (lane == owner) {
            L = t0;
            t0 = t1; t1 = t2; t2 = t3; t3 = ~0ull;
            --cnt;
        }
        if (lane == round) myWin = widx;
    }

    float sx = 0.f, sy = 0.f, sz = 0.f;
    if (lane < NK) {
        const float* p = xyz + ((size_t)b * NP + myWin) * 3;
        sx = p[0]; sy = p[1]; sz = p[2];
    }
    #pragma unroll
    for (int m = 32; m >= 1; m >>= 1) {
        sx += __shfl_xor(sx, m, 64);
        sy += __shfl_xor(sy, m, 64);
        sz += __shfl_xor(sz, m, 64);
    }
    if (lane == 0) {
        float* o = out + (size_t)NB * NG * 3 + ((size_t)b * NG + g) * 3;
        const float inv = 1.0f / 32.0f;   // /32 exact (power of 2)
        o[0] = sx * inv; o[1] = sy * inv; o[2] = sz * inv;
    }
}

extern "C" void kernel_launch(void* const* d_in, const int* in_sizes, int n_in,
                              void* d_out, int out_size, void* d_ws, size_t ws_size,
                              hipStream_t stream)
{
    const float* xyz = (const float*)d_in[0];
    float* out = (float*)d_out;

    hipLaunchKernelGGL(fps_kernel, dim3(NB), dim3(512), 0, stream, xyz, out);

    const int tasks  = NB * NG;            // 8192
    const int blocks = tasks / 4;          // 4 waves (tasks) per 256-thread block
    hipLaunchKernelGGL(knn_kernel, dim3(blocks), dim3(256), 0, stream, xyz, out);
}